// Round 7
// baseline (978.617 us; speedup 1.0000x reference)
//
#include <hip/hip_runtime.h>

// Problem constants (match reference setup_inputs)
#define NB    50000   // nodes
#define BB    64      // batch  (== wavefront size: lane = b)
#define DD    16      // neighbors per node
#define NDRVN 1000    // driver nodes

typedef float f2 __attribute__((ext_vector_type(2)));

// ---------------------------------------------------------------------------
// Force a (uniform) value into a VGPR (one v_mov from SGPR).  asm outputs are
// NOT rematerializable, so the allocator must keep these live (or scratch-
// spill, which WRITE_SIZE will expose) -- this pins weights in VGPRs.
__device__ __forceinline__ float vg(float s) {
    asm("" : "+v"(s));
    return s;
}
// Pack two uniform floats into one f2 VGPR pair: 2 v_movs, once per layer.
__device__ __forceinline__ f2 pack2(float lo, float hi) {
    f2 r;
    r.x = vg(lo);
    r.y = vg(hi);
    return r;
}

// relu on a packed pair -> v_pk_max_f32
__device__ __forceinline__ f2 relu2(f2 a) {
    return __builtin_elementwise_max(a, (f2)0.0f);
}

// ---------------------------------------------------------------------------
// VOP3P op_sel broadcast FMAs (numerics HW-verified R1/R3: absmax matched).
// Weights stay packed 2-per-64b-register: 76 VGPRs per 5x5 layer instead of
// 150 splats -- the ONLY weight representation whose total liveness
// (76 w + 6 b + ~140 data ~= 230) fits a 256-VGPR budget with no remat and
// no spill.  SCHEDULING NOTE: LLVM keeps INLINEASM in source order, so the
// conv loops below are written c-INNERMOST: consecutive asm fmas belong to
// different accumulator chains (dep distance 5 insts ~= 20 cyc >> ~6 cyc
// pk_fma latency).  R1/R3's regression was back-to-back tied chains in
// source order -- an order bug, not an asm-cost bug.
//
// acc += w.lo * in
__device__ __forceinline__ void fma_wlo(f2 w, f2 in, f2& acc) {
    asm("v_pk_fma_f32 %0, %1, %2, %0 op_sel_hi:[0,1,1]"
        : "+v"(acc) : "v"(w), "v"(in));
}
// acc += w.hi * in
__device__ __forceinline__ void fma_whi(f2 w, f2 in, f2& acc) {
    asm("v_pk_fma_f32 %0, %1, %2, %0 op_sel:[1,0,0] op_sel_hi:[1,1,1]"
        : "+v"(acc) : "v"(w), "v"(in));
}
// d = w.lo * in + b.lo
__device__ __forceinline__ f2 fma_wb_ll(f2 w, f2 in, f2 b) {
    f2 d;
    asm("v_pk_fma_f32 %0, %1, %2, %3 op_sel_hi:[0,1,0]"
        : "=v"(d) : "v"(w), "v"(in), "v"(b));
    return d;
}
// d = w.lo * in + b.hi
__device__ __forceinline__ f2 fma_wb_lh(f2 w, f2 in, f2 b) {
    f2 d;
    asm("v_pk_fma_f32 %0, %1, %2, %3 op_sel:[0,0,1] op_sel_hi:[0,1,1]"
        : "=v"(d) : "v"(w), "v"(in), "v"(b));
    return d;
}
// d = w.hi * in + b.lo
__device__ __forceinline__ f2 fma_wb_hl(f2 w, f2 in, f2 b) {
    f2 d;
    asm("v_pk_fma_f32 %0, %1, %2, %3 op_sel:[1,0,0] op_sel_hi:[1,1,0]"
        : "=v"(d) : "v"(w), "v"(in), "v"(b));
    return d;
}
// d = w.hi * in + b.hi
__device__ __forceinline__ f2 fma_wb_hh(f2 w, f2 in, f2 b) {
    f2 d;
    asm("v_pk_fma_f32 %0, %1, %2, %3 op_sel:[1,0,1] op_sel_hi:[1,1,1]"
        : "=v"(d) : "v"(w), "v"(in), "v"(b));
    return d;
}

// j is a compile-time constant after full unrolling -> branch folds away.
__device__ __forceinline__ void cstep(const f2* wp, int j, f2 in, f2& acc) {
    if (j & 1) fma_whi(wp[j >> 1], in, acc);
    else       fma_wlo(wp[j >> 1], in, acc);
}
// first tap: fold the bias into src2 via op_sel (no acc-init mov)
__device__ __forceinline__ f2 cbegin(const f2* wp, int jw, const f2* bp,
                                     int jb, f2 in) {
    f2 w = wp[jw >> 1], b = bp[jb >> 1];
    if (jw & 1) return (jb & 1) ? fma_wb_hh(w, in, b) : fma_wb_hl(w, in, b);
    else        return (jb & 1) ? fma_wb_lh(w, in, b) : fma_wb_ll(w, in, b);
}

// ---------------------------------------------------------------------------
// Weight staging: uniform derefs -> s_load batches, then v_mov pairs into
// packed f2 VGPRs (asm-pinned, non-remat).
__device__ __forceinline__ void load_w75(const float* __restrict__ w,
                                         const float* __restrict__ b,
                                         f2 (&wp)[38], f2 (&bp)[3]) {
#pragma unroll
    for (int i = 0; i < 37; ++i) wp[i] = pack2(w[2 * i], w[2 * i + 1]);
    wp[37] = pack2(w[74], 0.0f);
    bp[0] = pack2(b[0], b[1]);
    bp[1] = pack2(b[2], b[3]);
    bp[2] = pack2(b[4], 0.0f);
}

__device__ __forceinline__ void load_w15(const float* __restrict__ w,
                                         const float* __restrict__ b, int nb,
                                         f2 (&wp)[8], f2 (&bp)[3]) {
#pragma unroll
    for (int i = 0; i < 7; ++i) wp[i] = pack2(w[2 * i], w[2 * i + 1]);
    wp[7] = pack2(w[14], 0.0f);
    if (nb == 5) {
        bp[0] = pack2(b[0], b[1]);
        bp[1] = pack2(b[2], b[3]);
        bp[2] = pack2(b[4], 0.0f);
    } else {
        bp[0] = pack2(b[0], 0.0f);
        bp[1] = (f2)0.0f;
        bp[2] = (f2)0.0f;
    }
}

// ---------------------------------------------------------------------------
// Transpose x (B,N) -> z0 (N,B).
__global__ __launch_bounds__(256) void transpose_kernel(
    const float* __restrict__ x, float* __restrict__ xT)
{
    int tid = blockIdx.x * 256 + threadIdx.x;   // tid = n*64 + b
    int n = tid >> 6;
    int b = tid & 63;
    if (n < NB) xT[tid] = x[b * NB + n];
}

// ---------------------------------------------------------------------------
// One 5->5 conv1x3+relu layer for TWO nodes packed as f2 (.x=node A, .y=B).
// c-INNERMOST: the 5 channel accumulator asm chains interleave in source
// order (see scheduling note above).  Tap j in 0..14 -> (ci=j/3, t=j%3).
template<int WIN>
__device__ __forceinline__ void conv5p(const f2 (&in)[5][14], f2 (&out)[5][14],
                                       const f2 (&wp)[38], const f2 (&bp)[3])
{
    constexpr int WOUT = WIN - 2;
#pragma unroll
    for (int x = 0; x < WOUT; ++x) {
        f2 acc[5];
#pragma unroll
        for (int c = 0; c < 5; ++c)
            acc[c] = cbegin(wp, c * 15, bp, c, in[0][x]);   // j = 0
#pragma unroll
        for (int j = 1; j < 15; ++j) {
            const int ci = j / 3, t = j % 3;
#pragma unroll
            for (int c = 0; c < 5; ++c)
                cstep(wp, c * 15 + j, in[ci][x + t], acc[c]);
        }
#pragma unroll
        for (int c = 0; c < 5; ++c)
            out[c][x] = relu2(acc[c]);
    }
}

// ---------------------------------------------------------------------------
// One full pass, TWO nodes per wave packed into f2 lanes.
// waves_per_eu(2,2): 256-VGPR cap so the packed-weight liveness (~230 regs)
// fits with ZERO remat and ZERO spill.  2 waves/SIMD suffice: the kernel is
// issue-bound and the interleaved chains provide in-wave ILP.
__global__ __launch_bounds__(256)
__attribute__((amdgpu_waves_per_eu(2, 2)))
void pass_kernel(
    const float* __restrict__ zin, float* __restrict__ zout,
    const int*  __restrict__ nidx,
    const float* __restrict__ w0, const float* __restrict__ b0,
    const float* __restrict__ w1, const float* __restrict__ b1,
    const float* __restrict__ w2, const float* __restrict__ b2,
    const float* __restrict__ w3, const float* __restrict__ b3,
    const float* __restrict__ w4, const float* __restrict__ b4,
    const float* __restrict__ w5, const float* __restrict__ b5,
    const float* __restrict__ w6, const float* __restrict__ b6)
{
    int lane   = threadIdx.x & 63;
    int waveid = blockIdx.x * 4 + (threadIdx.x >> 6);     // 25000 waves
    int n0 = __builtin_amdgcn_readfirstlane(waveid * 2);  // nodes n0, n0+1

    // Neighbor indices for both nodes: 32 contiguous ints -> s_loads.
    const int* ip = nidx + n0 * DD;

    // Gather both nodes' neighborhoods into f2 pairs (.x = A, .y = B).
    f2 g[16];
#pragma unroll
    for (int d = 0; d < 16; ++d) {
        float a = zin[(size_t)ip[d]      * BB + lane];
        float b = zin[(size_t)ip[16 + d] * BB + lane];
        g[d] = (f2){a, b};
    }

    f2 ha[5][14], hb[5][14];

    // Layer 0: 1 -> 5 channels, width 16 -> 14 (c-innermost interleave)
    {
        f2 wp[8], bp[3];
        load_w15(w0, b0, 5, wp, bp);
#pragma unroll
        for (int x = 0; x < 14; ++x) {
            f2 acc[5];
#pragma unroll
            for (int c = 0; c < 5; ++c)
                acc[c] = cbegin(wp, c * 3, bp, c, g[x]);
#pragma unroll
            for (int j = 1; j < 3; ++j) {
#pragma unroll
                for (int c = 0; c < 5; ++c)
                    cstep(wp, c * 3 + j, g[x + j], acc[c]);
            }
#pragma unroll
            for (int c = 0; c < 5; ++c)
                ha[c][x] = relu2(acc[c]);
        }
    }

    { f2 wp[38], bp[3]; load_w75(w1, b1, wp, bp); conv5p<14>(ha, hb, wp, bp); }
    { f2 wp[38], bp[3]; load_w75(w2, b2, wp, bp); conv5p<12>(hb, ha, wp, bp); }
    { f2 wp[38], bp[3]; load_w75(w3, b3, wp, bp); conv5p<10>(ha, hb, wp, bp); }
    { f2 wp[38], bp[3]; load_w75(w4, b4, wp, bp); conv5p<8> (hb, ha, wp, bp); }
    { f2 wp[38], bp[3]; load_w75(w5, b5, wp, bp); conv5p<6> (ha, hb, wp, bp); }

    // Layer 6: 5 -> 1, width 4 -> 2, then pair-average.  Two chains (t0,t1)
    // alternate in source order: dep distance 2 insts ~= 8 cyc >= latency.
    {
        f2 wp[8], bp[3];
        load_w15(w6, b6, 1, wp, bp);
        f2 t0 = cbegin(wp, 0, bp, 0, hb[0][0]);
        f2 t1 = cbegin(wp, 0, bp, 0, hb[0][1]);
        cstep(wp, 1, hb[0][1], t0);
        cstep(wp, 1, hb[0][2], t1);
        cstep(wp, 2, hb[0][2], t0);
        cstep(wp, 2, hb[0][3], t1);
#pragma unroll
        for (int ci = 1; ci < 5; ++ci) {
#pragma unroll
            for (int t = 0; t < 3; ++t) {
                cstep(wp, ci * 3 + t, hb[ci][0 + t], t0);
                cstep(wp, ci * 3 + t, hb[ci][1 + t], t1);
            }
        }
        t0 = relu2(t0);
        t1 = relu2(t1);
        f2 o = (t0 + t1) * 0.5f;
        zout[(size_t)n0 * BB + lane]       = o.x;
        zout[(size_t)(n0 + 1) * BB + lane] = o.y;
    }
}

// ---------------------------------------------------------------------------
// Final driver gather: out[b, i] = z[driver_idx[i], b]   (out is (B, NDRV))
__global__ __launch_bounds__(256) void gather_out_kernel(
    const float* __restrict__ z, const int* __restrict__ didx,
    float* __restrict__ out)
{
    int i = blockIdx.x * 256 + threadIdx.x;
    if (i >= BB * NDRVN) return;
    int b = i / NDRVN;
    int k = i - b * NDRVN;
    out[i] = z[(size_t)didx[k] * BB + b];
}

// ---------------------------------------------------------------------------
extern "C" void kernel_launch(void* const* d_in, const int* in_sizes, int n_in,
                              void* d_out, int out_size, void* d_ws, size_t ws_size,
                              hipStream_t stream)
{
    const float* x    = (const float*)d_in[0];
    const int*   nidx = (const int*)  d_in[1];
    const int*   didx = (const int*)  d_in[2];
    const float* w[7];
    const float* b[7];
    for (int i = 0; i < 7; ++i) {
        w[i] = (const float*)d_in[3 + 2 * i];
        b[i] = (const float*)d_in[4 + 2 * i];
    }

    // Workspace: two ping-pong z buffers in (N, B) layout, 12.8 MB each.
    float* z0 = (float*)d_ws;
    float* z1 = z0 + (size_t)NB * BB;

    const int tblocks = (NB * BB) / 256;   // 12500 (transpose)
    const int pblocks = NB / 8;            // 6250: 4 waves x 2 nodes

    transpose_kernel<<<tblocks, 256, 0, stream>>>(x, z0);

    pass_kernel<<<pblocks, 256, 0, stream>>>(z0, z1, nidx,
        w[0], b[0], w[1], b[1], w[2], b[2], w[3], b[3],
        w[4], b[4], w[5], b[5], w[6], b[6]);
    pass_kernel<<<pblocks, 256, 0, stream>>>(z1, z0, nidx,
        w[0], b[0], w[1], b[1], w[2], b[2], w[3], b[3],
        w[4], b[4], w[5], b[5], w[6], b[6]);
    pass_kernel<<<pblocks, 256, 0, stream>>>(z0, z1, nidx,
        w[0], b[0], w[1], b[1], w[2], b[2], w[3], b[3],
        w[4], b[4], w[5], b[5], w[6], b[6]);
    pass_kernel<<<pblocks, 256, 0, stream>>>(z1, z0, nidx,
        w[0], b[0], w[1], b[1], w[2], b[2], w[3], b[3],
        w[4], b[4], w[5], b[5], w[6], b[6]);

    gather_out_kernel<<<(BB * NDRVN + 255) / 256, 256, 0, stream>>>(z0, didx, (float*)d_out);
}

// Round 8
// 961.852 us; speedup vs baseline: 1.0174x; 1.0174x over previous
//
#include <hip/hip_runtime.h>

// Problem constants (match reference setup_inputs)
#define NB    50000   // nodes
#define BB    64      // batch  (== wavefront size: lane = b)
#define DD    16      // neighbors per node
#define NDRVN 1000    // driver nodes

// ---------------------------------------------------------------------------
// Force a (uniform) value into a VGPR (one v_mov from SGPR).  v_fma with an
// SGPR broadcast operand issues at ~half the all-VGPR rate on gfx950, so
// weights get one mov each and then live in VGPRs.
__device__ __forceinline__ float vg(float s) {
    asm("" : "+v"(s));
    return s;
}

// ---------------------------------------------------------------------------
// Transpose x (B,N) -> z0 (N,B).
__global__ __launch_bounds__(256) void transpose_kernel(
    const float* __restrict__ x, float* __restrict__ xT)
{
    int tid = blockIdx.x * 256 + threadIdx.x;   // tid = n*64 + b
    int n = tid >> 6;
    int b = tid & 63;
    if (n < NB) xT[tid] = x[b * NB + n];
}

// ---------------------------------------------------------------------------
// One 5->5 conv1x3+relu layer, ONE node, scalar v_fma_f32 intrinsics (the
// compiler interleaves the 5 independent channel chains; rounds 1/3/7 proved
// inline-asm carries an inherent scheduling penalty).  Scalar + single-node
// is the MINIMUM-LIVENESS formulation: pk packing has zero throughput gain
// (pk@4cyc == 2x scalar@2cyc, established R0..R7) but doubles data liveness,
// which is what has been feeding allocator churn (remat movs / AGPR
// round-trips) in every previous round.
template<int WIN>
__device__ __forceinline__ void conv5s(const float (&in)[5][14], float (&out)[5][14],
                                       const float* __restrict__ w,
                                       const float* __restrict__ b)
{
    constexpr int WOUT = WIN - 2;
    float wr[75], bb[5];
#pragma unroll
    for (int t = 0; t < 75; ++t) wr[t] = vg(w[t]);
#pragma unroll
    for (int c = 0; c < 5; ++c) bb[c] = vg(b[c]);

#pragma unroll
    for (int x = 0; x < WOUT; ++x) {
#pragma unroll
        for (int c = 0; c < 5; ++c) {
            // bias folded into the first fma's addend: no acc-init mov
            float acc = fmaf(wr[c * 15 + 0], in[0][x + 0], bb[c]);
            acc = fmaf(wr[c * 15 + 1], in[0][x + 1], acc);
            acc = fmaf(wr[c * 15 + 2], in[0][x + 2], acc);
#pragma unroll
            for (int ci = 1; ci < 5; ++ci) {
                acc = fmaf(wr[c * 15 + ci * 3 + 0], in[ci][x + 0], acc);
                acc = fmaf(wr[c * 15 + ci * 3 + 1], in[ci][x + 1], acc);
                acc = fmaf(wr[c * 15 + ci * 3 + 2], in[ci][x + 2], acc);
            }
            out[c][x] = fmaxf(acc, 0.0f);
        }
    }
}

// ---------------------------------------------------------------------------
// Full 7-layer CNN for one node given its gathered neighborhood g[16].
__device__ __forceinline__ float cnn_node(
    const float (&g)[16],
    const float* __restrict__ w0, const float* __restrict__ b0,
    const float* __restrict__ w1, const float* __restrict__ b1,
    const float* __restrict__ w2, const float* __restrict__ b2,
    const float* __restrict__ w3, const float* __restrict__ b3,
    const float* __restrict__ w4, const float* __restrict__ b4,
    const float* __restrict__ w5, const float* __restrict__ b5,
    const float* __restrict__ w6, const float* __restrict__ b6)
{
    float ha[5][14], hb[5][14];

    // Layer 0: 1 -> 5 channels, width 16 -> 14
    {
        float wr[15], bb[5];
#pragma unroll
        for (int t = 0; t < 15; ++t) wr[t] = vg(w0[t]);
#pragma unroll
        for (int c = 0; c < 5; ++c) bb[c] = vg(b0[c]);
#pragma unroll
        for (int x = 0; x < 14; ++x) {
#pragma unroll
            for (int c = 0; c < 5; ++c) {
                float acc = fmaf(wr[c * 3 + 0], g[x + 0], bb[c]);
                acc = fmaf(wr[c * 3 + 1], g[x + 1], acc);
                acc = fmaf(wr[c * 3 + 2], g[x + 2], acc);
                ha[c][x] = fmaxf(acc, 0.0f);
            }
        }
    }

    conv5s<14>(ha, hb, w1, b1);   // 14 -> 12
    conv5s<12>(hb, ha, w2, b2);   // 12 -> 10
    conv5s<10>(ha, hb, w3, b3);   // 10 -> 8
    conv5s<8> (hb, ha, w4, b4);   // 8  -> 6
    conv5s<6> (ha, hb, w5, b5);   // 6  -> 4

    // Layer 6: 5 -> 1, width 4 -> 2, then pair-average.
    float wr[15];
#pragma unroll
    for (int t = 0; t < 15; ++t) wr[t] = vg(w6[t]);
    float bias = vg(b6[0]);

    float t0 = fmaf(wr[0], hb[0][0], bias);
    float t1 = fmaf(wr[0], hb[0][1], bias);
    t0 = fmaf(wr[1], hb[0][1], t0);
    t1 = fmaf(wr[1], hb[0][2], t1);
    t0 = fmaf(wr[2], hb[0][2], t0);
    t1 = fmaf(wr[2], hb[0][3], t1);
#pragma unroll
    for (int ci = 1; ci < 5; ++ci) {
#pragma unroll
        for (int t = 0; t < 3; ++t) {
            t0 = fmaf(wr[ci * 3 + t], hb[ci][0 + t], t0);
            t1 = fmaf(wr[ci * 3 + t], hb[ci][1 + t], t1);
        }
    }
    t0 = fmaxf(t0, 0.0f);
    t1 = fmaxf(t1, 0.0f);
    return 0.5f * (t0 + t1);
}

// ---------------------------------------------------------------------------
// One full pass: TWO nodes per wave, processed SEQUENTIALLY (not packed).
// All 32 gather loads issue upfront: node B's 16 stay outstanding through
// node A's entire ~7k-cycle compute (free prefetch; the compiler emits
// per-use vmcnt waits).  Data liveness stays at the 1-node level (~75
// floats) -- the lowest of any round -- so the allocator can keep the
// per-layer weights (80 regs, vg-pinned) genuinely live instead of
// remat/AGPR-shuffling them.
__global__ __launch_bounds__(256)
__attribute__((amdgpu_waves_per_eu(2, 8)))
void pass_kernel(
    const float* __restrict__ zin, float* __restrict__ zout,
    const int*  __restrict__ nidx,
    const float* __restrict__ w0, const float* __restrict__ b0,
    const float* __restrict__ w1, const float* __restrict__ b1,
    const float* __restrict__ w2, const float* __restrict__ b2,
    const float* __restrict__ w3, const float* __restrict__ b3,
    const float* __restrict__ w4, const float* __restrict__ b4,
    const float* __restrict__ w5, const float* __restrict__ b5,
    const float* __restrict__ w6, const float* __restrict__ b6)
{
    int lane   = threadIdx.x & 63;
    int waveid = blockIdx.x * 4 + (threadIdx.x >> 6);     // 25000 waves
    int n0 = __builtin_amdgcn_readfirstlane(waveid * 2);  // nodes n0, n0+1

    // Neighbor indices for both nodes: 32 contiguous ints -> s_loads.
    const int* ip = nidx + n0 * DD;

    // Issue both gathers back-to-back; B's loads are the prefetch.
    float g0[16], g1[16];
#pragma unroll
    for (int d = 0; d < 16; ++d)
        g0[d] = zin[(size_t)ip[d] * BB + lane];
#pragma unroll
    for (int d = 0; d < 16; ++d)
        g1[d] = zin[(size_t)ip[16 + d] * BB + lane];

    float oA = cnn_node(g0, w0, b0, w1, b1, w2, b2, w3, b3, w4, b4, w5, b5, w6, b6);
    zout[(size_t)n0 * BB + lane] = oA;

    float oB = cnn_node(g1, w0, b0, w1, b1, w2, b2, w3, b3, w4, b4, w5, b5, w6, b6);
    zout[(size_t)(n0 + 1) * BB + lane] = oB;
}

// ---------------------------------------------------------------------------
// Final driver gather: out[b, i] = z[driver_idx[i], b]   (out is (B, NDRV))
__global__ __launch_bounds__(256) void gather_out_kernel(
    const float* __restrict__ z, const int* __restrict__ didx,
    float* __restrict__ out)
{
    int i = blockIdx.x * 256 + threadIdx.x;
    if (i >= BB * NDRVN) return;
    int b = i / NDRVN;
    int k = i - b * NDRVN;
    out[i] = z[(size_t)didx[k] * BB + b];
}

// ---------------------------------------------------------------------------
extern "C" void kernel_launch(void* const* d_in, const int* in_sizes, int n_in,
                              void* d_out, int out_size, void* d_ws, size_t ws_size,
                              hipStream_t stream)
{
    const float* x    = (const float*)d_in[0];
    const int*   nidx = (const int*)  d_in[1];
    const int*   didx = (const int*)  d_in[2];
    const float* w[7];
    const float* b[7];
    for (int i = 0; i < 7; ++i) {
        w[i] = (const float*)d_in[3 + 2 * i];
        b[i] = (const float*)d_in[4 + 2 * i];
    }

    // Workspace: two ping-pong z buffers in (N, B) layout, 12.8 MB each.
    float* z0 = (float*)d_ws;
    float* z1 = z0 + (size_t)NB * BB;

    const int tblocks = (NB * BB) / 256;   // 12500 (transpose)
    const int pblocks = NB / 8;            // 6250: 4 waves x 2 sequential nodes

    transpose_kernel<<<tblocks, 256, 0, stream>>>(x, z0);

    pass_kernel<<<pblocks, 256, 0, stream>>>(z0, z1, nidx,
        w[0], b[0], w[1], b[1], w[2], b[2], w[3], b[3],
        w[4], b[4], w[5], b[5], w[6], b[6]);
    pass_kernel<<<pblocks, 256, 0, stream>>>(z1, z0, nidx,
        w[0], b[0], w[1], b[1], w[2], b[2], w[3], b[3],
        w[4], b[4], w[5], b[5], w[6], b[6]);
    pass_kernel<<<pblocks, 256, 0, stream>>>(z0, z1, nidx,
        w[0], b[0], w[1], b[1], w[2], b[2], w[3], b[3],
        w[4], b[4], w[5], b[5], w[6], b[6]);
    pass_kernel<<<pblocks, 256, 0, stream>>>(z1, z0, nidx,
        w[0], b[0], w[1], b[1], w[2], b[2], w[3], b[3],
        w[4], b[4], w[5], b[5], w[6], b[6]);

    gather_out_kernel<<<(BB * NDRVN + 255) / 256, 256, 0, stream>>>(z0, didx, (float*)d_out);
}